// Round 10
// baseline (3776.962 us; speedup 1.0000x reference)
//
#include <hip/hip_runtime.h>
#include <math.h>

// ---------------- problem constants ----------------
#define NZ 8
#define T_H 36
#define NVAR 502
#define MCON 769
#define NITERS 150
#define SIGMA 1e-6f
#define BIGINF 1e20f
#define ROWS 2
#define MEET 17          // twisted-factorization meet block

// constraint row offsets
#define R_XLB 9
#define R_XUB 81
#define R_UBOX 153
#define R_UEQ 223
#define R_DYN 275
#define R_SDYN 555
#define R_SLB 590
#define R_SUB 625
#define R_TGT 660
#define R_XSNN 661
#define R_SSNN 733

// global-var offsets (original ordering)
#define NUOFF 288
#define NSOFF 358
#define NXSOFF 394
#define NSSOFF 466

// ws layout (float offsets)
#define OFF_A      0          // A[769][512]
#define OFF_CSRV   393728     // [769][12]
#define OFF_CSRC   402956     // [769][12] ints
#define OFF_CSCV   412184     // [502][16]
#define OFF_CSCR   420216     // [502][16] ints
#define OFF_M      428248     // M[502][512] (dead after k_meet; reused for packed pairs)
#define OFF_CSRP   428248     // [769][12][2] packed (val, idx-bits)
#define OFF_CSCP   446704     // [502][16][2]
#define OFF_SINV   685272     // 36*196  S_t (top)
#define OFF_G      692328     // 36*196  G_t (top)
#define OFF_GP     699384     // 36*256  G rows padded
#define OFF_GTP    708600     // 36*256  G^T rows padded
#define OFF_SVP    717816     // 36*256  S rows padded
#define OFF_HP     727032     // 36*256  H_t rows padded (bottom elim)
#define OFF_SVTP   736248     // 36*256  S~_t rows padded
#define OFF_KP     745464     // 36*256  K_t rows padded
#define OFF_WP     754680     // 256     W (meet) rows padded
#define OFF_L0     956408     // [769]
#define OFF_U0     957177     // [769]

__device__ __forceinline__ int pcol(int v){
    if (v < 288){ int t = v >> 3, j = v & 7; return 14*t + j; }
    if (v < 358){ int q = v - 288; int t = q >> 1, k = q & 1; return 14*t + 8 + k; }
    if (v < 394){ int t = v - 358; return (t < 35) ? (14*t + 10) : 498; }
    if (v < 466){ int q = v - 394; int t = q >> 1, k = q & 1; return (t < 35) ? (14*t + 11 + k) : (499 + k); }
    int t = v - 466; return (t < 35) ? (14*t + 13) : 501;
}

__device__ __forceinline__ float rho_of(int r){
    if (r <= 8) return 1000.f;
    if (r >= R_UEQ && r < R_SLB) return 1000.f;
    return 1.f;
}

__device__ __forceinline__ float pdiag_p(int p){
    if (p < 490){ int s = p % 14; return (s >= 11) ? 20000.f : 0.f; }
    int s = p - 490; return (s >= 9) ? 20000.f : 0.f;
}

// ---------------- K1: build permuted dense A ----------------
__global__ __launch_bounds__(256) void k_build_A(const float* __restrict__ Az,
                                                 const float* __restrict__ Au,
                                                 const float* __restrict__ ZtoX,
                                                 float* __restrict__ ws){
    float* A = ws + OFF_A;
    int tid = threadIdx.x;
    for (int i = tid; i < 769*512; i += 256) A[i] = 0.f;
    __syncthreads();
    for (int i = tid; i < 8; i += 256) A[i*512 + pcol(i)] += 1.f;
    if (tid == 0) A[8*512 + pcol(NSOFF)] += 1.f;
    for (int idx = tid; idx < 576; idx += 256){
        int t = idx >> 4, k = (idx >> 3) & 1, j = idx & 7;
        float v = ZtoX[k*8 + j];
        int c = pcol(8*t + j);
        A[(R_XLB + 2*t + k)*512 + c] += v;
        A[(R_XUB + 2*t + k)*512 + c] += v;
    }
    for (int idx = tid; idx < 72; idx += 256){
        int c = pcol(NXSOFF + idx);
        A[(R_XLB + idx)*512 + c] += 1.f;
        A[(R_XUB + idx)*512 + c] -= 1.f;
    }
    for (int idx = tid; idx < 70; idx += 256) A[(R_UBOX + idx)*512 + pcol(NUOFF + idx)] += 1.f;
    for (int idx = tid; idx < 52; idx += 256){
        int i = idx >> 1, kk = idx & 1;
        int t = (i/3)*4 + (i%3) + 1;
        A[(R_UEQ + idx)*512 + pcol(NUOFF + 2*t + kk)]       += 1.f;
        A[(R_UEQ + idx)*512 + pcol(NUOFF + 2*(t-1) + kk)]   -= 1.f;
    }
    for (int idx = tid; idx < 2240; idx += 256){
        int t = idx/64 + 1, rem = idx % 64, j = rem >> 3, k = rem & 7;
        A[(R_DYN + 8*(t-1) + j)*512 + pcol(8*(t-1) + k)] += Az[j*8 + k];
    }
    for (int idx = tid; idx < 560; idx += 256){
        int t = idx/16 + 1, rem = idx % 16, j = rem >> 1, ju = rem & 1;
        A[(R_DYN + 8*(t-1) + j)*512 + pcol(NUOFF + 2*(t-1) + ju)] += Au[j*2 + ju];
    }
    for (int idx = tid; idx < 280; idx += 256){
        int t = (idx >> 3) + 1, j = idx & 7;
        A[(R_DYN + 8*(t-1) + j)*512 + pcol(8*t + j)] -= 1.f;
    }
    for (int idx = tid; idx < 35; idx += 256){
        int t = idx + 1; int rb = (R_SDYN + idx)*512;
        A[rb + pcol(NSOFF + t)]     += 1.f;
        A[rb + pcol(NSOFF + t - 1)] -= 1.f;
        A[rb + pcol(NUOFF + 2*(t-1))] += -0.05f;
    }
    for (int idx = tid; idx < 35; idx += 256){
        int t = idx + 1;
        A[(R_SLB + idx)*512 + pcol(NSOFF + t)]  += 1.f;
        A[(R_SLB + idx)*512 + pcol(NSSOFF + t)] += 1.f;
        A[(R_SUB + idx)*512 + pcol(NSOFF + t)]  += 1.f;
        A[(R_SUB + idx)*512 + pcol(NSSOFF + t)] -= 1.f;
    }
    if (tid == 0){
        A[R_TGT*512 + pcol(NSOFF + 35)]  += 1.f;
        A[R_TGT*512 + pcol(NSSOFF + 35)] += 1.f;
    }
    for (int idx = tid; idx < 72; idx += 256) A[(R_XSNN + idx)*512 + pcol(NXSOFF + idx)] += 1.f;
    for (int idx = tid; idx < 36; idx += 256) A[(R_SSNN + idx)*512 + pcol(NSSOFF + idx)] += 1.f;
}

// ---------------- K2: CSR(12) / CSC(16) ----------------
__global__ __launch_bounds__(256) void k_sparse(float* __restrict__ ws){
    const float* A = ws + OFF_A;
    float* crv = ws + OFF_CSRV; int* crc = (int*)(ws + OFF_CSRC);
    float* ccv = ws + OFF_CSCV; int* ccr = (int*)(ws + OFF_CSCR);
    int job = blockIdx.x*256 + threadIdx.x;
    if (job < 769){
        int r = job, n = 0;
        for (int c = 0; c < 502; ++c){
            float v = A[r*512 + c];
            if (v != 0.f && n < 12){ crv[r*12 + n] = v; crc[r*12 + n] = c; ++n; }
        }
        for (; n < 12; ++n){ crv[r*12 + n] = 0.f; crc[r*12 + n] = 0; }
    } else if (job < 1271){
        int c = job - 769, n = 0;
        for (int r = 0; r < 769; ++r){
            float v = A[r*512 + c];
            if (v != 0.f && n < 16){ ccv[c*16 + n] = v; ccr[c*16 + n] = r; ++n; }
        }
        for (; n < 16; ++n){ ccv[c*16 + n] = 0.f; ccr[c*16 + n] = 0; }
    }
}

// ---------------- K3: M = diag(P+sigma) + A^T rho A ----------------
__global__ __launch_bounds__(256) void k_build_M(float* __restrict__ ws){
    const float* A = ws + OFF_A;
    const float* ccv = ws + OFF_CSCV; const int* ccr = (const int*)(ws + OFF_CSCR);
    float* M = ws + OFF_M;
    int gid = blockIdx.x*256 + threadIdx.x;
    int i = gid >> 9, j = gid & 511;
    if (j >= 502) return;
    float acc = 0.f;
    #pragma unroll
    for (int s = 0; s < 16; ++s){
        float v = ccv[i*16 + s]; int r = ccr[i*16 + s];
        acc += v * rho_of(r) * A[r*512 + j];
    }
    if (i == j) acc += pdiag_p(i) + SIGMA;
    M[i*512 + j] = acc;
}

// ---------------- K4: both factorizations in one kernel (block 0 = top-down, block 1 = bottom-up) ----------------
__global__ __launch_bounds__(256) void k_factor_both(float* __restrict__ ws){
    const float* M = ws + OFF_M;
    __shared__ float Sp[196], Bn[196], Hl[196], Bl[196], fcol[14];
    __shared__ float aug[14*28];
    __shared__ float piv;
    int tid = threadIdx.x;
    if (blockIdx.x == 0){
        // -------- top-down LDL: G_t, S_t --------
        float* Gout = ws + OFF_G;
        float* Sout = ws + OFF_SINV;
        for (int t = 0; t < 36; ++t){
            int bs = (t < 35) ? 14 : 12;
            int bo = 14*t;
            for (int idx = tid; idx < bs*bs; idx += 256){ int i = idx/bs, j = idx%bs; aug[i*28 + j] = M[(bo+i)*512 + bo + j]; }
            for (int idx = tid; idx < bs*bs; idx += 256){ int i = idx/bs, j = idx%bs; aug[i*28 + 14 + j] = (i==j) ? 1.f : 0.f; }
            if (t > 0){
                for (int idx = tid; idx < 196; idx += 256){ int i = idx/14, j = idx%14; Bn[idx] = (i < bs) ? M[(bo+i)*512 + (bo-14) + j] : 0.f; }
                __syncthreads();
                for (int idx = tid; idx < 196; idx += 256){
                    int i = idx/14, j = idx%14; float a = 0.f;
                    #pragma unroll
                    for (int k = 0; k < 14; ++k) a += Bn[i*14 + k]*Sp[k*14 + j];
                    Hl[idx] = a; Gout[t*196 + idx] = a;
                }
                __syncthreads();
                for (int idx = tid; idx < bs*bs; idx += 256){
                    int i = idx/bs, j = idx%bs; float a = 0.f;
                    #pragma unroll
                    for (int k = 0; k < 14; ++k) a += Hl[i*14 + k]*Bn[j*14 + k];
                    aug[i*28 + j] -= a;
                }
            }
            __syncthreads();
            for (int k = 0; k < bs; ++k){
                if (tid == 0) piv = 1.f/aug[k*28 + k];
                if (tid < bs) fcol[tid] = aug[tid*28 + k];
                __syncthreads();
                for (int j = tid; j < 2*bs; j += 256){ int col = (j < bs) ? j : (14 + j - bs); aug[k*28 + col] *= piv; }
                __syncthreads();
                for (int idx = tid; idx < bs*2*bs; idx += 256){
                    int i = idx/(2*bs), jj = idx%(2*bs);
                    int col = (jj < bs) ? jj : (14 + jj - bs);
                    if (i != k) aug[i*28 + col] -= fcol[i]*aug[k*28 + col];
                }
                __syncthreads();
            }
            for (int idx = tid; idx < 196; idx += 256){
                int i = idx/14, j = idx%14;
                float v = (i < bs && j < bs) ? aug[i*28 + 14 + j] : 0.f;
                Sout[t*196 + idx] = v; Sp[idx] = v;
            }
            __syncthreads();
        }
    } else {
        // -------- bottom-up (twisted): H_t, S~_t, K_t --------
        float* HP  = ws + OFF_HP;
        float* SVT = ws + OFF_SVTP;
        float* KP  = ws + OFF_KP;
        for (int t = 35; t >= 0; --t){
            int bs = (t < 35) ? 14 : 12;
            int bo = 14*t;
            for (int idx = tid; idx < bs*bs; idx += 256){ int i = idx/bs, j = idx%bs; aug[i*28 + j] = M[(bo+i)*512 + bo + j]; }
            for (int idx = tid; idx < bs*bs; idx += 256){ int i = idx/bs, j = idx%bs; aug[i*28 + 14 + j] = (i==j) ? 1.f : 0.f; }
            if (t < 35){
                int bs1 = (t+1 < 35) ? 14 : 12;
                for (int idx = tid; idx < 196; idx += 256){ int i = idx/14, j = idx%14; Bn[idx] = (i < bs1) ? M[(14*(t+1)+i)*512 + bo + j] : 0.f; }
                __syncthreads();
                for (int idx = tid; idx < 196; idx += 256){
                    int i = idx/14, j = idx%14; float a = 0.f;
                    #pragma unroll
                    for (int k = 0; k < 14; ++k) a += Bn[k*14 + i]*Sp[k*14 + j];
                    Hl[idx] = a;
                }
                __syncthreads();
                { int i = tid >> 4, j = tid & 15; HP[t*256 + tid] = (i < 14 && j < 14) ? Hl[i*14 + j] : 0.f; }
                for (int idx = tid; idx < bs*bs; idx += 256){
                    int i = idx/bs, j = idx%bs; float a = 0.f;
                    #pragma unroll
                    for (int k = 0; k < 14; ++k) a += Hl[i*14 + k]*Bn[k*14 + j];
                    aug[i*28 + j] -= a;
                }
            }
            __syncthreads();
            for (int k = 0; k < bs; ++k){
                if (tid == 0) piv = 1.f/aug[k*28 + k];
                if (tid < bs) fcol[tid] = aug[tid*28 + k];
                __syncthreads();
                for (int j = tid; j < 2*bs; j += 256){ int col = (j < bs) ? j : (14 + j - bs); aug[k*28 + col] *= piv; }
                __syncthreads();
                for (int idx = tid; idx < bs*2*bs; idx += 256){
                    int i = idx/(2*bs), jj = idx%(2*bs);
                    int col = (jj < bs) ? jj : (14 + jj - bs);
                    if (i != k) aug[i*28 + col] -= fcol[i]*aug[k*28 + col];
                }
                __syncthreads();
            }
            for (int idx = tid; idx < 196; idx += 256){
                int i = idx/14, j = idx%14;
                Sp[idx] = (i < bs && j < bs) ? aug[i*28 + 14 + j] : 0.f;
            }
            __syncthreads();
            { int i = tid >> 4, j = tid & 15; SVT[t*256 + tid] = (i < 14 && j < 14) ? Sp[i*14 + j] : 0.f; }
            if (t >= 1){
                for (int idx = tid; idx < 196; idx += 256){ int i = idx/14, j = idx%14; Bl[idx] = (i < bs) ? M[(bo+i)*512 + (bo-14) + j] : 0.f; }
                __syncthreads();
                { int i = tid >> 4, j = tid & 15;
                  float a = 0.f;
                  if (i < 14 && j < 14){
                      #pragma unroll
                      for (int k = 0; k < 14; ++k) a += Sp[i*14 + k]*Bl[k*14 + j];
                  }
                  KP[t*256 + tid] = a; }
            }
            __syncthreads();
        }
    }
}

// ---------------- K4c: meet matrix W = (D_m - G_m B_m^T - H_m B_{m+1})^{-1} ----------------
__global__ __launch_bounds__(256) void k_meet(float* __restrict__ ws){
    const float* M = ws + OFF_M;
    const float* Gout = ws + OFF_G;
    const float* HP = ws + OFF_HP;
    float* WP = ws + OFF_WP;
    __shared__ float Stp[196], Bn[196], Hl[196], Bl[196], fcol[14];
    __shared__ float aug[14*28];
    __shared__ float piv;
    int tid = threadIdx.x;
    const int m = MEET, bo = 14*MEET;
    for (int idx = tid; idx < 196; idx += 256){ int i = idx/14, j = idx%14; Bn[idx] = M[(bo+i)*512 + (bo-14) + j]; }     // B_m
    for (int idx = tid; idx < 196; idx += 256){ int i = idx/14, j = idx%14; Bl[idx] = M[(14*(m+1)+i)*512 + bo + j]; }    // B_{m+1}
    for (int idx = tid; idx < 196; idx += 256){ int i = idx/14, j = idx%14; Hl[idx] = HP[m*256 + i*16 + j]; }            // H_m
    for (int idx = tid; idx < 196; idx += 256){ Stp[idx] = Gout[m*196 + idx]; }                                          // G_m
    __syncthreads();
    for (int idx = tid; idx < 196; idx += 256){
        int i = idx/14, j = idx%14;
        float a = M[(bo+i)*512 + bo + j];
        #pragma unroll
        for (int k = 0; k < 14; ++k) a -= Stp[i*14 + k]*Bn[j*14 + k];   // G_m B_m^T
        #pragma unroll
        for (int k = 0; k < 14; ++k) a -= Hl[i*14 + k]*Bl[k*14 + j];    // H_m B_{m+1}
        aug[i*28 + j] = a;
    }
    for (int idx = tid; idx < 196; idx += 256){ int i = idx/14, j = idx%14; aug[i*28 + 14 + j] = (i==j) ? 1.f : 0.f; }
    __syncthreads();
    const int bs = 14;
    for (int k = 0; k < bs; ++k){
        if (tid == 0) piv = 1.f/aug[k*28 + k];
        if (tid < bs) fcol[tid] = aug[tid*28 + k];
        __syncthreads();
        for (int j = tid; j < 2*bs; j += 256){ int col = (j < bs) ? j : (14 + j - bs); aug[k*28 + col] *= piv; }
        __syncthreads();
        for (int idx = tid; idx < bs*2*bs; idx += 256){
            int i = idx/(2*bs), jj = idx%(2*bs);
            int col = (jj < bs) ? jj : (14 + jj - bs);
            if (i != k) aug[i*28 + col] -= fcol[i]*aug[k*28 + col];
        }
        __syncthreads();
    }
    { int i = tid >> 4, j = tid & 15; WP[tid] = (i < 14 && j < 14) ? aug[i*28 + 14 + j] : 0.f; }
}

// ---------------- K5a: pack top factors into padded [36][16][16] ----------------
__global__ __launch_bounds__(256) void k_pack(float* __restrict__ ws){
    int t = blockIdx.x;
    int e = threadIdx.x;
    int i = e >> 4, j = e & 15;
    bool in = (i < 14) && (j < 14);
    float g  = in ? ws[OFF_G    + t*196 + i*14 + j] : 0.f;
    float gt = in ? ws[OFF_G    + t*196 + j*14 + i] : 0.f;
    float sv = in ? ws[OFF_SINV + t*196 + i*14 + j] : 0.f;
    ws[OFF_GP  + t*256 + e] = g;
    ws[OFF_GTP + t*256 + e] = gt;
    ws[OFF_SVP + t*256 + e] = sv;
}

// ---------------- K5b: pack CSR/CSC into (val, idx) pairs (clobbers M) ----------------
__global__ __launch_bounds__(256) void k_packsp(float* __restrict__ ws){
    int* wsi = (int*)ws;
    int idx = blockIdx.x*256 + threadIdx.x;
    if (idx < 9228){
        wsi[OFF_CSRP + 2*idx]     = wsi[OFF_CSRV + idx];
        wsi[OFF_CSRP + 2*idx + 1] = wsi[OFF_CSRC + idx];
    } else if (idx < 9228 + 8032){
        int j = idx - 9228;
        wsi[OFF_CSCP + 2*j]     = wsi[OFF_CSCV + j];
        wsi[OFF_CSCP + 2*j + 1] = wsi[OFF_CSCR + j];
    }
}

// ---------------- K6: batch-uniform bounds ----------------
__global__ __launch_bounds__(256) void k_bounds(const float* __restrict__ Xlb_p, const float* __restrict__ Xub_p,
                                                const float* __restrict__ slb_p, const float* __restrict__ sub_p,
                                                const float* __restrict__ tgt_p, float* __restrict__ ws){
    __shared__ float sc[8];
    float* L0 = ws + OFF_L0; float* U0 = ws + OFF_U0;
    int tid = threadIdx.x;
    if (tid == 0){
        sc[0] = tanhf(Xlb_p[0])*0.5f; sc[1] = tanhf(Xlb_p[1])*0.5f;
        sc[2] = tanhf(Xub_p[0])*0.5f; sc[3] = tanhf(Xub_p[1])*0.5f;
        sc[4] = tanhf(slb_p[0])*0.5f; sc[5] = tanhf(sub_p[0])*0.5f;
        sc[6] = tanhf(tgt_p[0]);
    }
    __syncthreads();
    for (int r = tid; r < 769; r += 256){
        float l = -BIGINF, u = BIGINF;
        if (r < 9){ l = 0.f; u = 0.f; }
        else if (r < R_XUB){ l = -1.f + sc[(r - R_XLB) & 1]; }
        else if (r < R_UBOX){ u = 1.f + sc[2 + ((r - R_XUB) & 1)]; }
        else if (r < R_UEQ){ l = -1.f; u = 1.f; }
        else if (r < R_SLB){ l = 0.f; u = 0.f; }
        else if (r < R_SUB){ l = sc[4]; }
        else if (r < R_TGT){ u = 6.f + sc[5]; }
        else if (r == R_TGT){ l = 1.f + sc[6]; }
        else { l = 0.f; }
        L0[r] = l; U0[r] = u;
    }
}

// 16-term padded-row dot, two accumulators
#define DOT16(a0v, a1v, m0, m1, m2, m3, c0, c1, c2, c3) \
    a0v = fmaf(m0.x, c0.x, a0v); a1v = fmaf(m0.y, c0.y, a1v); \
    a0v = fmaf(m0.z, c0.z, a0v); a1v = fmaf(m0.w, c0.w, a1v); \
    a0v = fmaf(m1.x, c1.x, a0v); a1v = fmaf(m1.y, c1.y, a1v); \
    a0v = fmaf(m1.z, c1.z, a0v); a1v = fmaf(m1.w, c1.w, a1v); \
    a0v = fmaf(m2.x, c2.x, a0v); a1v = fmaf(m2.y, c2.y, a1v); \
    a0v = fmaf(m2.z, c2.z, a0v); a1v = fmaf(m2.w, c2.w, a1v); \
    a0v = fmaf(m3.x, c3.x, a0v); a1v = fmaf(m3.y, c3.y, a1v); \
    a0v = fmaf(m3.z, c3.z, a0v); a1v = fmaf(m3.w, c3.w, a1v);

#define LD4X4(p, v0, v1, v2, v3) \
    v0 = *(const float4*)((p) + 0);  v1 = *(const float4*)((p) + 4); \
    v2 = *(const float4*)((p) + 8);  v3 = *(const float4*)((p) + 12);

// ---------------- K7: persistent fused ADMM, twisted (BABE) solve, 512 threads ----------------
// 512 blocks x 512 thr, ROWS=2. Phase A: 1 col/thread. Phase B: <=2 rows/thread.
// Solve on wave 0 (64 lanes): (li 0..15) x (lr row 0..1) x (dir 0=top,1=bottom).
__global__ __launch_bounds__(512) void k_admm(const float* __restrict__ feat,
                                              const float* __restrict__ XtoZ,
                                              const float* __restrict__ ws,
                                              float* __restrict__ out){
    const float* L0 = ws + OFF_L0; const float* U0 = ws + OFF_U0;

    __shared__ __align__(16) float buf[512][ROWS];     // x / rhs, [col][row]
    __shared__ __align__(16) float yyT[769][ROWS];
    __shared__ __align__(16) float wwT[769][ROWS];
    __shared__ __align__(16) float crb[36][ROWS][20];  // c_t (t<=16) / d_t (t>=18)
    __shared__ __align__(16) float mid[2][ROWS][20];
    __shared__ __align__(16) float tmv[ROWS][20];
    __shared__ __align__(16) float xpv[2][ROWS][20];
    __shared__ float l0s[769], u0s[769];
    __shared__ float zi[ROWS][12];
    __shared__ float pr[ROWS][12];

    int tid = threadIdx.x;
    int b0 = blockIdx.x*ROWS;

    for (int i = tid; i < 769; i += 512){ l0s[i] = L0[i]; u0s[i] = U0[i]; }
    for (int i = tid; i < 512*ROWS; i += 512) (&buf[0][0])[i] = 0.f;
    for (int i = tid; i < 769*ROWS; i += 512){ (&yyT[0][0])[i] = 0.f; (&wwT[0][0])[i] = 0.f; }
    for (int i = tid; i < 36*ROWS*20; i += 512) (&crb[0][0][0])[i] = 0.f;
    if (tid < 2*ROWS*20){ (&mid[0][0][0])[tid] = 0.f; (&xpv[0][0][0])[tid] = 0.f; }
    if (tid < ROWS*20) (&tmv[0][0])[tid] = 0.f;
    if (tid < 12*ROWS){ int r = tid/12, k = tid%12; pr[r][k] = (k < 9) ? feat[(b0+r)*12 + 3 + k] : 0.f; }
    if (tid < ROWS){
        float s0 = feat[(b0+tid)*12 + 0], s1 = feat[(b0+tid)*12 + 1];
        #pragma unroll
        for (int j = 0; j < 8; ++j) zi[tid][j] = s0*XtoZ[j*2 + 0] + s1*XtoZ[j*2 + 1];
        zi[tid][8] = feat[(b0+tid)*12 + 2];
    }
    __syncthreads();

    for (int it = 0; it < NITERS; ++it){
        // -------- phase A: rhs = sigma*x - q + w@A (packed CSC, 1 col/thread) --------
        if (tid < 502){
            int c = tid;
            float r0 = SIGMA*buf[c][0], r1 = SIGMA*buf[c][1];
            int t14 = c/14, s14 = c - t14*14;
            if (c < 490 && s14 == 9){ int pi = t14 >> 2; r0 -= pr[0][pi]; r1 -= pr[1][pi]; }
            const float4* pp = (const float4*)(ws + OFF_CSCP + c*32);
            #pragma unroll
            for (int s = 0; s < 8; ++s){
                float4 p4 = pp[s];
                int ra = __float_as_int(p4.y), rb = __float_as_int(p4.w);
                r0 += p4.x*wwT[ra][0]; r1 += p4.x*wwT[ra][1];
                r0 += p4.z*wwT[rb][0]; r1 += p4.z*wwT[rb][1];
            }
            buf[c][0] = r0; buf[c][1] = r1;
        }
        __syncthreads();
        // -------- twisted block-tridiag solve (wave 0, 64 lanes) --------
        if (tid < 64){
            const int li  = tid & 15;
            const int lr  = (tid >> 4) & 1;
            const int dir = tid >> 5;
            {
                int ti = dir ? 35 : 0;
                crb[ti][lr][li] = (li < 14) ? buf[14*ti + li][lr] : 0.f;
            }
            const float* EB = dir ? (ws + OFF_HP) : (ws + OFF_GP);
            float4 g0, g1, g2, g3;
            { int t0 = dir ? 34 : 1; LD4X4(EB + t0*256 + li*16, g0, g1, g2, g3) }
            for (int k = 0; k < 17; ++k){
                bool act  = dir ? true : (k <= 15);
                int t     = dir ? (34 - k) : (k + 1);
                int tp    = dir ? (t + 1) : (t - 1);
                bool nact = dir ? ((k+1) <= 16) : ((k+1) <= 15);
                int tn    = nact ? (dir ? (34 - (k+1)) : (k + 2)) : t;
                float4 n0, n1, n2, n3;
                LD4X4(EB + tn*256 + li*16, n0, n1, n2, n3)
                float4 c0, c1, c2, c3;
                LD4X4(&crb[tp][lr][0], c0, c1, c2, c3)
                float b = (act && li < 14) ? buf[14*t + li][lr] : 0.f;
                float a0 = 0.f, a1 = 0.f;
                DOT16(a0, a1, g0, g1, g2, g3, c0, c1, c2, c3)
                float nc = b - a0 - a1;
                if (act) crb[t][lr][li] = nc;
                g0 = n0; g1 = n1; g2 = n2; g3 = n3;
            }
            // meet: x_m = W (b_m - G_m c_{m-1} - H_m d_{m+1})
            {
                const float* mr = (dir ? (ws + OFF_HP) : (ws + OFF_GP)) + MEET*256 + li*16;
                float4 m0, m1, m2, m3;  LD4X4(mr, m0, m1, m2, m3)
                int tc = dir ? (MEET + 1) : (MEET - 1);
                float4 c0, c1, c2, c3;  LD4X4(&crb[tc][lr][0], c0, c1, c2, c3)
                float p0 = 0.f, p1 = 0.f;
                DOT16(p0, p1, m0, m1, m2, m3, c0, c1, c2, c3)
                mid[dir][lr][li] = p0 + p1;
                float bm = (li < 14) ? buf[14*MEET + li][lr] : 0.f;
                float tv = bm - mid[0][lr][li] - mid[1][lr][li];
                if (!dir) tmv[lr][li] = tv;
                float4 w0, w1, w2, w3;  LD4X4(ws + OFF_WP + li*16, w0, w1, w2, w3)
                float4 t0, t1, t2, t3;  LD4X4(&tmv[lr][0], t0, t1, t2, t3)
                float a0 = 0.f, a1 = 0.f;
                DOT16(a0, a1, w0, w1, w2, w3, t0, t1, t2, t3)
                float xm = a0 + a1;
                xpv[dir][lr][li] = xm;
                if (!dir && li < 14) buf[14*MEET + li][lr] = xm;
            }
            // back-sub outward
            const float* SB = dir ? (ws + OFF_SVTP) : (ws + OFF_SVP);
            const float* KB = dir ? (ws + OFF_KP)   : (ws + OFF_GTP);
            for (int k = 0; k < 18; ++k){
                bool act = dir ? true : (k <= 16);
                int t   = dir ? (MEET + 1 + k) : (MEET - 1 - k);
                int tc  = act ? t : 0;
                int tk  = dir ? tc : (tc + 1);
                float4 s0, s1, s2, s3;  LD4X4(SB + tc*256 + li*16, s0, s1, s2, s3)
                float4 k0, k1, k2, k3;  LD4X4(KB + tk*256 + li*16, k0, k1, k2, k3)
                float4 c0, c1, c2, c3;  LD4X4(&crb[tc][lr][0], c0, c1, c2, c3)
                float4 x0, x1, x2, x3;  LD4X4(&xpv[dir][lr][0], x0, x1, x2, x3)
                float a0 = 0.f, a1 = 0.f, d0 = 0.f, d1 = 0.f;
                DOT16(a0, a1, s0, s1, s2, s3, c0, c1, c2, c3)
                DOT16(d0, d1, k0, k1, k2, k3, x0, x1, x2, x3)
                float x = (a0 + a1) - (d0 + d1);
                if (act){
                    xpv[dir][lr][li] = x;
                    if (li < 14) buf[14*t + li][lr] = x;
                }
            }
        }
        __syncthreads();
        // -------- phase B: Ax (packed CSR), clip, y/w update --------
        for (int rr = tid; rr < 769; rr += 512){
            float rho = rho_of(rr);
            float rinv = 1.f/rho;
            float ax0 = 0.f, ax1 = 0.f;
            const float4* pp = (const float4*)(ws + OFF_CSRP + rr*24);
            #pragma unroll
            for (int s = 0; s < 6; ++s){
                float4 p4 = pp[s];
                int ca = __float_as_int(p4.y), cb = __float_as_int(p4.w);
                ax0 += p4.x*buf[ca][0]; ax1 += p4.x*buf[ca][1];
                ax0 += p4.z*buf[cb][0]; ax1 += p4.z*buf[cb][1];
            }
            float lb = 0.f, ub = 0.f;
            if (rr >= 9){ lb = l0s[rr]; ub = u0s[rr]; }
            float yv0 = yyT[rr][0], yv1 = yyT[rr][1];
            float li0, ui0, li1, ui1;
            if (rr < 9){ li0 = ui0 = zi[0][rr]; li1 = ui1 = zi[1][rr]; }
            else { li0 = li1 = lb; ui0 = ui1 = ub; }
            float v0 = ax0 + yv0*rinv;
            float v1 = ax1 + yv1*rinv;
            float z0 = fminf(fmaxf(v0, li0), ui0);
            float z1 = fminf(fmaxf(v1, li1), ui1);
            float yn0 = yv0 + rho*(ax0 - z0);
            float yn1 = yv1 + rho*(ax1 - z1);
            yyT[rr][0] = yn0; yyT[rr][1] = yn1;
            wwT[rr][0] = rho*z0 - yn0; wwT[rr][1] = rho*z1 - yn1;
        }
        __syncthreads();
    }
    if (tid < ROWS*2){ int r = tid >> 1, k = tid & 1; out[(b0 + r)*2 + k] = buf[8 + k][r]; }
}

// ---------------- K8: critic MLP ----------------
__global__ __launch_bounds__(64) void k_critic(const float* __restrict__ feat,
    const float* __restrict__ Ws,  const float* __restrict__ bs_,
    const float* __restrict__ Wst, const float* __restrict__ bst,
    const float* __restrict__ Wipr,const float* __restrict__ bipr,
    const float* __restrict__ Wp,  const float* __restrict__ bp,
    const float* __restrict__ Ws1, const float* __restrict__ bs1,
    const float* __restrict__ Wst1,const float* __restrict__ bst1,
    const float* __restrict__ Wipr1,const float* __restrict__ bipr1,
    const float* __restrict__ Wp1, const float* __restrict__ bp1,
    const float* __restrict__ Wf1, const float* __restrict__ bf1,
    const float* __restrict__ Wf2, const float* __restrict__ bf2,
    float* __restrict__ out){
    __shared__ float hL[64][65];
    __shared__ float h2L[64][65];
    int tid = threadIdx.x;
    int b = blockIdx.x*64 + tid;
    const float* f = feat + b*12;
    float st0 = f[0], st1 = f[1], sg = f[2];
    float p[9];
    #pragma unroll
    for (int j = 0; j < 9; ++j) p[j] = f[3 + j];
    float pmx = p[0], pmn = p[0];
    #pragma unroll
    for (int j = 1; j < 9; ++j){ pmx = fmaxf(pmx, p[j]); pmn = fminf(pmn, p[j]); }
    float t1[24], t2[8];
    #pragma unroll
    for (int o = 0; o < 24; ++o) t1[o] = fmaxf(0.f, st0*Ws[o*2] + st1*Ws[o*2 + 1] + bs_[o]);
    #pragma unroll
    for (int o = 0; o < 24; ++o){ float a = bs1[o];
        #pragma unroll
        for (int j = 0; j < 24; ++j) a += t1[j]*Ws1[o*24 + j];
        hL[tid][o] = fmaxf(0.f, a); }
    #pragma unroll
    for (int o = 0; o < 8; ++o) t2[o] = fmaxf(0.f, sg*Wst[o] + bst[o]);
    #pragma unroll
    for (int o = 0; o < 8; ++o){ float a = bst1[o];
        #pragma unroll
        for (int j = 0; j < 8; ++j) a += t2[j]*Wst1[o*8 + j];
        hL[tid][24 + o] = fmaxf(0.f, a); }
    float i1 = pmx - pmn;
    #pragma unroll
    for (int o = 0; o < 8; ++o) t2[o] = fmaxf(0.f, p[0]*Wipr[o*2] + i1*Wipr[o*2 + 1] + bipr[o]);
    #pragma unroll
    for (int o = 0; o < 8; ++o){ float a = bipr1[o];
        #pragma unroll
        for (int j = 0; j < 8; ++j) a += t2[j]*Wipr1[o*8 + j];
        hL[tid][32 + o] = fmaxf(0.f, a); }
    #pragma unroll
    for (int o = 0; o < 24; ++o){ float a = bp[o];
        #pragma unroll
        for (int j = 0; j < 9; ++j) a += p[j]*Wp[o*9 + j];
        t1[o] = fmaxf(0.f, a); }
    #pragma unroll
    for (int o = 0; o < 24; ++o){ float a = bp1[o];
        #pragma unroll
        for (int j = 0; j < 24; ++j) a += t1[j]*Wp1[o*24 + j];
        hL[tid][40 + o] = fmaxf(0.f, a); }
    for (int o = 0; o < 64; ++o){ float a = bf1[o];
        for (int j = 0; j < 64; ++j) a += hL[tid][j]*Wf1[o*64 + j];
        h2L[tid][o] = fmaxf(0.f, a); }
    for (int o = 0; o < 64; ++o){ float a = bf2[o];
        for (int j = 0; j < 64; ++j) a += h2L[tid][j]*Wf2[o*64 + j];
        out[2048 + b*64 + o] = fmaxf(0.f, a); }
}

extern "C" void kernel_launch(void* const* d_in, const int* in_sizes, int n_in,
                              void* d_out, int out_size, void* d_ws, size_t ws_size,
                              hipStream_t stream){
    (void)in_sizes; (void)n_in; (void)out_size; (void)ws_size;
    const float* feat  = (const float*)d_in[0];
    const float* Xlb_p = (const float*)d_in[1];
    const float* Xub_p = (const float*)d_in[2];
    const float* slb_p = (const float*)d_in[3];
    const float* sub_p = (const float*)d_in[4];
    const float* tgt_p = (const float*)d_in[5];
    const float* Az    = (const float*)d_in[6];
    const float* Au    = (const float*)d_in[7];
    const float* ZtoX  = (const float*)d_in[8];
    const float* XtoZ  = (const float*)d_in[9];
    float* ws  = (float*)d_ws;
    float* out = (float*)d_out;

    hipLaunchKernelGGL(k_build_A,     dim3(1),    dim3(256), 0, stream, Az, Au, ZtoX, ws);
    hipLaunchKernelGGL(k_sparse,      dim3(5),    dim3(256), 0, stream, ws);
    hipLaunchKernelGGL(k_build_M,     dim3(1004), dim3(256), 0, stream, ws);
    hipLaunchKernelGGL(k_factor_both, dim3(2),    dim3(256), 0, stream, ws);
    hipLaunchKernelGGL(k_meet,        dim3(1),    dim3(256), 0, stream, ws);
    hipLaunchKernelGGL(k_pack,        dim3(36),   dim3(256), 0, stream, ws);
    hipLaunchKernelGGL(k_packsp,      dim3(68),   dim3(256), 0, stream, ws);
    hipLaunchKernelGGL(k_bounds,      dim3(1),    dim3(256), 0, stream, Xlb_p, Xub_p, slb_p, sub_p, tgt_p, ws);
    hipLaunchKernelGGL(k_admm,        dim3(512),  dim3(512), 0, stream, feat, XtoZ, ws, out);
    hipLaunchKernelGGL(k_critic,      dim3(16),   dim3(64),  0, stream, feat,
        (const float*)d_in[10], (const float*)d_in[11], (const float*)d_in[12], (const float*)d_in[13],
        (const float*)d_in[14], (const float*)d_in[15], (const float*)d_in[16], (const float*)d_in[17],
        (const float*)d_in[18], (const float*)d_in[19], (const float*)d_in[20], (const float*)d_in[21],
        (const float*)d_in[22], (const float*)d_in[23], (const float*)d_in[24], (const float*)d_in[25],
        (const float*)d_in[26], (const float*)d_in[27], (const float*)d_in[28], (const float*)d_in[29],
        out);
}

// Round 12
// 2836.652 us; speedup vs baseline: 1.3315x; 1.3315x over previous
//
#include <hip/hip_runtime.h>
#include <math.h>

// ---------------- problem constants ----------------
#define NZ 8
#define T_H 36
#define NVAR 502
#define MCON 769
#define NITERS 150
#define SIGMA 1e-6f
#define BIGINF 1e20f
#define ROWS 2
#define MEET 17          // twisted-factorization meet block

// constraint row offsets
#define R_XLB 9
#define R_XUB 81
#define R_UBOX 153
#define R_UEQ 223
#define R_DYN 275
#define R_SDYN 555
#define R_SLB 590
#define R_SUB 625
#define R_TGT 660
#define R_XSNN 661
#define R_SSNN 733

// global-var offsets (original ordering)
#define NUOFF 288
#define NSOFF 358
#define NXSOFF 394
#define NSSOFF 466

// ws layout (float offsets)
#define OFF_A      0          // A[769][512]
#define OFF_CSRV   393728     // [769][12]
#define OFF_CSRC   402956     // [769][12] ints
#define OFF_CSCV   412184     // [502][16]
#define OFF_CSCR   420216     // [502][16] ints
#define OFF_M      428248     // M[502][512] (dead after k_meet; reused for packed pairs)
#define OFF_CSRP   428248     // [769][12][2] packed (val, idx-bits)
#define OFF_CSCP   446704     // [502][16][2]
#define OFF_SINV   685272     // 36*196  S_t (top)
#define OFF_G      692328     // 36*196  G_t (top)
#define OFF_GP     699384     // 36*256  G rows padded
#define OFF_GTP    708600     // 36*256  G^T rows padded
#define OFF_SVP    717816     // 36*256  S rows padded
#define OFF_HP     727032     // 36*256  H_t rows padded (bottom elim)
#define OFF_SVTP   736248     // 36*256  S~_t rows padded
#define OFF_KP     745464     // 36*256  K_t rows padded
#define OFF_WP     754680     // 256     W (meet) rows padded
#define OFF_L0     956408     // [769]
#define OFF_U0     957177     // [769]

__device__ __forceinline__ int pcol(int v){
    if (v < 288){ int t = v >> 3, j = v & 7; return 14*t + j; }
    if (v < 358){ int q = v - 288; int t = q >> 1, k = q & 1; return 14*t + 8 + k; }
    if (v < 394){ int t = v - 358; return (t < 35) ? (14*t + 10) : 498; }
    if (v < 466){ int q = v - 394; int t = q >> 1, k = q & 1; return (t < 35) ? (14*t + 11 + k) : (499 + k); }
    int t = v - 466; return (t < 35) ? (14*t + 13) : 501;
}

__device__ __forceinline__ float rho_of(int r){
    if (r <= 8) return 1000.f;
    if (r >= R_UEQ && r < R_SLB) return 1000.f;
    return 1.f;
}

__device__ __forceinline__ float pdiag_p(int p){
    if (p < 490){ int s = p % 14; return (s >= 11) ? 20000.f : 0.f; }
    int s = p - 490; return (s >= 9) ? 20000.f : 0.f;
}

// ---------------- K1: build permuted dense A ----------------
__global__ __launch_bounds__(256) void k_build_A(const float* __restrict__ Az,
                                                 const float* __restrict__ Au,
                                                 const float* __restrict__ ZtoX,
                                                 float* __restrict__ ws){
    float* A = ws + OFF_A;
    int tid = threadIdx.x;
    for (int i = tid; i < 769*512; i += 256) A[i] = 0.f;
    __syncthreads();
    for (int i = tid; i < 8; i += 256) A[i*512 + pcol(i)] += 1.f;
    if (tid == 0) A[8*512 + pcol(NSOFF)] += 1.f;
    for (int idx = tid; idx < 576; idx += 256){
        int t = idx >> 4, k = (idx >> 3) & 1, j = idx & 7;
        float v = ZtoX[k*8 + j];
        int c = pcol(8*t + j);
        A[(R_XLB + 2*t + k)*512 + c] += v;
        A[(R_XUB + 2*t + k)*512 + c] += v;
    }
    for (int idx = tid; idx < 72; idx += 256){
        int c = pcol(NXSOFF + idx);
        A[(R_XLB + idx)*512 + c] += 1.f;
        A[(R_XUB + idx)*512 + c] -= 1.f;
    }
    for (int idx = tid; idx < 70; idx += 256) A[(R_UBOX + idx)*512 + pcol(NUOFF + idx)] += 1.f;
    for (int idx = tid; idx < 52; idx += 256){
        int i = idx >> 1, kk = idx & 1;
        int t = (i/3)*4 + (i%3) + 1;
        A[(R_UEQ + idx)*512 + pcol(NUOFF + 2*t + kk)]       += 1.f;
        A[(R_UEQ + idx)*512 + pcol(NUOFF + 2*(t-1) + kk)]   -= 1.f;
    }
    for (int idx = tid; idx < 2240; idx += 256){
        int t = idx/64 + 1, rem = idx % 64, j = rem >> 3, k = rem & 7;
        A[(R_DYN + 8*(t-1) + j)*512 + pcol(8*(t-1) + k)] += Az[j*8 + k];
    }
    for (int idx = tid; idx < 560; idx += 256){
        int t = idx/16 + 1, rem = idx % 16, j = rem >> 1, ju = rem & 1;
        A[(R_DYN + 8*(t-1) + j)*512 + pcol(NUOFF + 2*(t-1) + ju)] += Au[j*2 + ju];
    }
    for (int idx = tid; idx < 280; idx += 256){
        int t = (idx >> 3) + 1, j = idx & 7;
        A[(R_DYN + 8*(t-1) + j)*512 + pcol(8*t + j)] -= 1.f;
    }
    for (int idx = tid; idx < 35; idx += 256){
        int t = idx + 1; int rb = (R_SDYN + idx)*512;
        A[rb + pcol(NSOFF + t)]     += 1.f;
        A[rb + pcol(NSOFF + t - 1)] -= 1.f;
        A[rb + pcol(NUOFF + 2*(t-1))] += -0.05f;
    }
    for (int idx = tid; idx < 35; idx += 256){
        int t = idx + 1;
        A[(R_SLB + idx)*512 + pcol(NSOFF + t)]  += 1.f;
        A[(R_SLB + idx)*512 + pcol(NSSOFF + t)] += 1.f;
        A[(R_SUB + idx)*512 + pcol(NSOFF + t)]  += 1.f;
        A[(R_SUB + idx)*512 + pcol(NSSOFF + t)] -= 1.f;
    }
    if (tid == 0){
        A[R_TGT*512 + pcol(NSOFF + 35)]  += 1.f;
        A[R_TGT*512 + pcol(NSSOFF + 35)] += 1.f;
    }
    for (int idx = tid; idx < 72; idx += 256) A[(R_XSNN + idx)*512 + pcol(NXSOFF + idx)] += 1.f;
    for (int idx = tid; idx < 36; idx += 256) A[(R_SSNN + idx)*512 + pcol(NSSOFF + idx)] += 1.f;
}

// ---------------- K2: CSR(12) / CSC(16) ----------------
__global__ __launch_bounds__(256) void k_sparse(float* __restrict__ ws){
    const float* A = ws + OFF_A;
    float* crv = ws + OFF_CSRV; int* crc = (int*)(ws + OFF_CSRC);
    float* ccv = ws + OFF_CSCV; int* ccr = (int*)(ws + OFF_CSCR);
    int job = blockIdx.x*256 + threadIdx.x;
    if (job < 769){
        int r = job, n = 0;
        for (int c = 0; c < 502; ++c){
            float v = A[r*512 + c];
            if (v != 0.f && n < 12){ crv[r*12 + n] = v; crc[r*12 + n] = c; ++n; }
        }
        for (; n < 12; ++n){ crv[r*12 + n] = 0.f; crc[r*12 + n] = 0; }
    } else if (job < 1271){
        int c = job - 769, n = 0;
        for (int r = 0; r < 769; ++r){
            float v = A[r*512 + c];
            if (v != 0.f && n < 16){ ccv[c*16 + n] = v; ccr[c*16 + n] = r; ++n; }
        }
        for (; n < 16; ++n){ ccv[c*16 + n] = 0.f; ccr[c*16 + n] = 0; }
    }
}

// ---------------- K3: M = diag(P+sigma) + A^T rho A ----------------
__global__ __launch_bounds__(256) void k_build_M(float* __restrict__ ws){
    const float* A = ws + OFF_A;
    const float* ccv = ws + OFF_CSCV; const int* ccr = (const int*)(ws + OFF_CSCR);
    float* M = ws + OFF_M;
    int gid = blockIdx.x*256 + threadIdx.x;
    int i = gid >> 9, j = gid & 511;
    if (j >= 502) return;
    float acc = 0.f;
    #pragma unroll
    for (int s = 0; s < 16; ++s){
        float v = ccv[i*16 + s]; int r = ccr[i*16 + s];
        acc += v * rho_of(r) * A[r*512 + j];
    }
    if (i == j) acc += pdiag_p(i) + SIGMA;
    M[i*512 + j] = acc;
}

// ---------------- K4: both factorizations in one kernel (block 0 = top-down, block 1 = bottom-up) ----------------
__global__ __launch_bounds__(256) void k_factor_both(float* __restrict__ ws){
    const float* M = ws + OFF_M;
    __shared__ float Sp[196], Bn[196], Hl[196], Bl[196], fcol[14];
    __shared__ float aug[14*28];
    __shared__ float piv;
    int tid = threadIdx.x;
    if (blockIdx.x == 0){
        // -------- top-down LDL: G_t, S_t --------
        float* Gout = ws + OFF_G;
        float* Sout = ws + OFF_SINV;
        for (int t = 0; t < 36; ++t){
            int bs = (t < 35) ? 14 : 12;
            int bo = 14*t;
            for (int idx = tid; idx < bs*bs; idx += 256){ int i = idx/bs, j = idx%bs; aug[i*28 + j] = M[(bo+i)*512 + bo + j]; }
            for (int idx = tid; idx < bs*bs; idx += 256){ int i = idx/bs, j = idx%bs; aug[i*28 + 14 + j] = (i==j) ? 1.f : 0.f; }
            if (t > 0){
                for (int idx = tid; idx < 196; idx += 256){ int i = idx/14, j = idx%14; Bn[idx] = (i < bs) ? M[(bo+i)*512 + (bo-14) + j] : 0.f; }
                __syncthreads();
                for (int idx = tid; idx < 196; idx += 256){
                    int i = idx/14, j = idx%14; float a = 0.f;
                    #pragma unroll
                    for (int k = 0; k < 14; ++k) a += Bn[i*14 + k]*Sp[k*14 + j];
                    Hl[idx] = a; Gout[t*196 + idx] = a;
                }
                __syncthreads();
                for (int idx = tid; idx < bs*bs; idx += 256){
                    int i = idx/bs, j = idx%bs; float a = 0.f;
                    #pragma unroll
                    for (int k = 0; k < 14; ++k) a += Hl[i*14 + k]*Bn[j*14 + k];
                    aug[i*28 + j] -= a;
                }
            }
            __syncthreads();
            for (int k = 0; k < bs; ++k){
                if (tid == 0) piv = 1.f/aug[k*28 + k];
                if (tid < bs) fcol[tid] = aug[tid*28 + k];
                __syncthreads();
                for (int j = tid; j < 2*bs; j += 256){ int col = (j < bs) ? j : (14 + j - bs); aug[k*28 + col] *= piv; }
                __syncthreads();
                for (int idx = tid; idx < bs*2*bs; idx += 256){
                    int i = idx/(2*bs), jj = idx%(2*bs);
                    int col = (jj < bs) ? jj : (14 + jj - bs);
                    if (i != k) aug[i*28 + col] -= fcol[i]*aug[k*28 + col];
                }
                __syncthreads();
            }
            for (int idx = tid; idx < 196; idx += 256){
                int i = idx/14, j = idx%14;
                float v = (i < bs && j < bs) ? aug[i*28 + 14 + j] : 0.f;
                Sout[t*196 + idx] = v; Sp[idx] = v;
            }
            __syncthreads();
        }
    } else {
        // -------- bottom-up (twisted): H_t, S~_t, K_t --------
        float* HP  = ws + OFF_HP;
        float* SVT = ws + OFF_SVTP;
        float* KP  = ws + OFF_KP;
        for (int t = 35; t >= 0; --t){
            int bs = (t < 35) ? 14 : 12;
            int bo = 14*t;
            for (int idx = tid; idx < bs*bs; idx += 256){ int i = idx/bs, j = idx%bs; aug[i*28 + j] = M[(bo+i)*512 + bo + j]; }
            for (int idx = tid; idx < bs*bs; idx += 256){ int i = idx/bs, j = idx%bs; aug[i*28 + 14 + j] = (i==j) ? 1.f : 0.f; }
            if (t < 35){
                int bs1 = (t+1 < 35) ? 14 : 12;
                for (int idx = tid; idx < 196; idx += 256){ int i = idx/14, j = idx%14; Bn[idx] = (i < bs1) ? M[(14*(t+1)+i)*512 + bo + j] : 0.f; }
                __syncthreads();
                for (int idx = tid; idx < 196; idx += 256){
                    int i = idx/14, j = idx%14; float a = 0.f;
                    #pragma unroll
                    for (int k = 0; k < 14; ++k) a += Bn[k*14 + i]*Sp[k*14 + j];
                    Hl[idx] = a;
                }
                __syncthreads();
                { int i = tid >> 4, j = tid & 15; HP[t*256 + tid] = (i < 14 && j < 14) ? Hl[i*14 + j] : 0.f; }
                for (int idx = tid; idx < bs*bs; idx += 256){
                    int i = idx/bs, j = idx%bs; float a = 0.f;
                    #pragma unroll
                    for (int k = 0; k < 14; ++k) a += Hl[i*14 + k]*Bn[k*14 + j];
                    aug[i*28 + j] -= a;
                }
            }
            __syncthreads();
            for (int k = 0; k < bs; ++k){
                if (tid == 0) piv = 1.f/aug[k*28 + k];
                if (tid < bs) fcol[tid] = aug[tid*28 + k];
                __syncthreads();
                for (int j = tid; j < 2*bs; j += 256){ int col = (j < bs) ? j : (14 + j - bs); aug[k*28 + col] *= piv; }
                __syncthreads();
                for (int idx = tid; idx < bs*2*bs; idx += 256){
                    int i = idx/(2*bs), jj = idx%(2*bs);
                    int col = (jj < bs) ? jj : (14 + jj - bs);
                    if (i != k) aug[i*28 + col] -= fcol[i]*aug[k*28 + col];
                }
                __syncthreads();
            }
            for (int idx = tid; idx < 196; idx += 256){
                int i = idx/14, j = idx%14;
                Sp[idx] = (i < bs && j < bs) ? aug[i*28 + 14 + j] : 0.f;
            }
            __syncthreads();
            { int i = tid >> 4, j = tid & 15; SVT[t*256 + tid] = (i < 14 && j < 14) ? Sp[i*14 + j] : 0.f; }
            if (t >= 1){
                for (int idx = tid; idx < 196; idx += 256){ int i = idx/14, j = idx%14; Bl[idx] = (i < bs) ? M[(bo+i)*512 + (bo-14) + j] : 0.f; }
                __syncthreads();
                { int i = tid >> 4, j = tid & 15;
                  float a = 0.f;
                  if (i < 14 && j < 14){
                      #pragma unroll
                      for (int k = 0; k < 14; ++k) a += Sp[i*14 + k]*Bl[k*14 + j];
                  }
                  KP[t*256 + tid] = a; }
            }
            __syncthreads();
        }
    }
}

// ---------------- K4c: meet matrix W = (D_m - G_m B_m^T - H_m B_{m+1})^{-1} ----------------
__global__ __launch_bounds__(256) void k_meet(float* __restrict__ ws){
    const float* M = ws + OFF_M;
    const float* Gout = ws + OFF_G;
    const float* HP = ws + OFF_HP;
    float* WP = ws + OFF_WP;
    __shared__ float Stp[196], Bn[196], Hl[196], Bl[196], fcol[14];
    __shared__ float aug[14*28];
    __shared__ float piv;
    int tid = threadIdx.x;
    const int m = MEET, bo = 14*MEET;
    for (int idx = tid; idx < 196; idx += 256){ int i = idx/14, j = idx%14; Bn[idx] = M[(bo+i)*512 + (bo-14) + j]; }     // B_m
    for (int idx = tid; idx < 196; idx += 256){ int i = idx/14, j = idx%14; Bl[idx] = M[(14*(m+1)+i)*512 + bo + j]; }    // B_{m+1}
    for (int idx = tid; idx < 196; idx += 256){ int i = idx/14, j = idx%14; Hl[idx] = HP[m*256 + i*16 + j]; }            // H_m
    for (int idx = tid; idx < 196; idx += 256){ Stp[idx] = Gout[m*196 + idx]; }                                          // G_m
    __syncthreads();
    for (int idx = tid; idx < 196; idx += 256){
        int i = idx/14, j = idx%14;
        float a = M[(bo+i)*512 + bo + j];
        #pragma unroll
        for (int k = 0; k < 14; ++k) a -= Stp[i*14 + k]*Bn[j*14 + k];   // G_m B_m^T
        #pragma unroll
        for (int k = 0; k < 14; ++k) a -= Hl[i*14 + k]*Bl[k*14 + j];    // H_m B_{m+1}
        aug[i*28 + j] = a;
    }
    for (int idx = tid; idx < 196; idx += 256){ int i = idx/14, j = idx%14; aug[i*28 + 14 + j] = (i==j) ? 1.f : 0.f; }
    __syncthreads();
    const int bs = 14;
    for (int k = 0; k < bs; ++k){
        if (tid == 0) piv = 1.f/aug[k*28 + k];
        if (tid < bs) fcol[tid] = aug[tid*28 + k];
        __syncthreads();
        for (int j = tid; j < 2*bs; j += 256){ int col = (j < bs) ? j : (14 + j - bs); aug[k*28 + col] *= piv; }
        __syncthreads();
        for (int idx = tid; idx < bs*2*bs; idx += 256){
            int i = idx/(2*bs), jj = idx%(2*bs);
            int col = (jj < bs) ? jj : (14 + jj - bs);
            if (i != k) aug[i*28 + col] -= fcol[i]*aug[k*28 + col];
        }
        __syncthreads();
    }
    { int i = tid >> 4, j = tid & 15; WP[tid] = (i < 14 && j < 14) ? aug[i*28 + 14 + j] : 0.f; }
}

// ---------------- K5: merged epilogue: pack factors (blocks 0-35), pack CSR/CSC (36-103), bounds (104) ----------------
__global__ __launch_bounds__(256) void k_finish(const float* __restrict__ Xlb_p, const float* __restrict__ Xub_p,
                                                const float* __restrict__ slb_p, const float* __restrict__ sub_p,
                                                const float* __restrict__ tgt_p, float* __restrict__ ws){
    int blk = blockIdx.x;
    int tid = threadIdx.x;
    if (blk < 36){
        int t = blk, e = tid;
        int i = e >> 4, j = e & 15;
        bool in = (i < 14) && (j < 14);
        float g  = in ? ws[OFF_G    + t*196 + i*14 + j] : 0.f;
        float gt = in ? ws[OFF_G    + t*196 + j*14 + i] : 0.f;
        float sv = in ? ws[OFF_SINV + t*196 + i*14 + j] : 0.f;
        ws[OFF_GP  + t*256 + e] = g;
        ws[OFF_GTP + t*256 + e] = gt;
        ws[OFF_SVP + t*256 + e] = sv;
    } else if (blk < 104){
        int* wsi = (int*)ws;
        int idx = (blk - 36)*256 + tid;
        if (idx < 9228){
            wsi[OFF_CSRP + 2*idx]     = wsi[OFF_CSRV + idx];
            wsi[OFF_CSRP + 2*idx + 1] = wsi[OFF_CSRC + idx];
        } else if (idx < 9228 + 8032){
            int j = idx - 9228;
            wsi[OFF_CSCP + 2*j]     = wsi[OFF_CSCV + j];
            wsi[OFF_CSCP + 2*j + 1] = wsi[OFF_CSCR + j];
        }
    } else {
        __shared__ float sc[8];
        float* L0 = ws + OFF_L0; float* U0 = ws + OFF_U0;
        if (tid == 0){
            sc[0] = tanhf(Xlb_p[0])*0.5f; sc[1] = tanhf(Xlb_p[1])*0.5f;
            sc[2] = tanhf(Xub_p[0])*0.5f; sc[3] = tanhf(Xub_p[1])*0.5f;
            sc[4] = tanhf(slb_p[0])*0.5f; sc[5] = tanhf(sub_p[0])*0.5f;
            sc[6] = tanhf(tgt_p[0]);
        }
        __syncthreads();
        for (int r = tid; r < 769; r += 256){
            float l = -BIGINF, u = BIGINF;
            if (r < 9){ l = 0.f; u = 0.f; }
            else if (r < R_XUB){ l = -1.f + sc[(r - R_XLB) & 1]; }
            else if (r < R_UBOX){ u = 1.f + sc[2 + ((r - R_XUB) & 1)]; }
            else if (r < R_UEQ){ l = -1.f; u = 1.f; }
            else if (r < R_SLB){ l = 0.f; u = 0.f; }
            else if (r < R_SUB){ l = sc[4]; }
            else if (r < R_TGT){ u = 6.f + sc[5]; }
            else if (r == R_TGT){ l = 1.f + sc[6]; }
            else { l = 0.f; }
            L0[r] = l; U0[r] = u;
        }
    }
}

// 16-term padded-row dot, two accumulators
#define DOT16(a0v, a1v, m0, m1, m2, m3, c0, c1, c2, c3) \
    a0v = fmaf(m0.x, c0.x, a0v); a1v = fmaf(m0.y, c0.y, a1v); \
    a0v = fmaf(m0.z, c0.z, a0v); a1v = fmaf(m0.w, c0.w, a1v); \
    a0v = fmaf(m1.x, c1.x, a0v); a1v = fmaf(m1.y, c1.y, a1v); \
    a0v = fmaf(m1.z, c1.z, a0v); a1v = fmaf(m1.w, c1.w, a1v); \
    a0v = fmaf(m2.x, c2.x, a0v); a1v = fmaf(m2.y, c2.y, a1v); \
    a0v = fmaf(m2.z, c2.z, a0v); a1v = fmaf(m2.w, c2.w, a1v); \
    a0v = fmaf(m3.x, c3.x, a0v); a1v = fmaf(m3.y, c3.y, a1v); \
    a0v = fmaf(m3.z, c3.z, a0v); a1v = fmaf(m3.w, c3.w, a1v);

#define LD4X4(p, v0, v1, v2, v3) \
    v0 = *(const float4*)((p) + 0);  v1 = *(const float4*)((p) + 4); \
    v2 = *(const float4*)((p) + 8);  v3 = *(const float4*)((p) + 12);

// ---------------- K7: persistent fused ADMM, twisted (BABE) solve, 256 threads ----------------
// 512 blocks x 256 thr, ROWS=2 -> 2 blocks/CU: one block's serial solve overlaps the
// co-resident block's phases A/B. Solve on wave 0 (64 lanes): (li)x(lr)x(dir).
__global__ __launch_bounds__(256) void k_admm(const float* __restrict__ feat,
                                              const float* __restrict__ XtoZ,
                                              const float* __restrict__ ws,
                                              float* __restrict__ out){
    const float* L0 = ws + OFF_L0; const float* U0 = ws + OFF_U0;

    __shared__ __align__(16) float buf[512][ROWS];     // x / rhs, [col][row]
    __shared__ __align__(16) float yyT[769][ROWS];
    __shared__ __align__(16) float wwT[769][ROWS];
    __shared__ __align__(16) float crb[36][ROWS][20];  // c_t (t<=16) / d_t (t>=18)
    __shared__ __align__(16) float mid[2][ROWS][20];
    __shared__ __align__(16) float tmv[ROWS][20];
    __shared__ __align__(16) float xpv[2][ROWS][20];
    __shared__ float l0s[769], u0s[769];
    __shared__ float zi[ROWS][12];
    __shared__ float pr[ROWS][12];

    int tid = threadIdx.x;
    int b0 = blockIdx.x*ROWS;

    for (int i = tid; i < 769; i += 256){ l0s[i] = L0[i]; u0s[i] = U0[i]; }
    for (int i = tid; i < 512*ROWS; i += 256) (&buf[0][0])[i] = 0.f;
    for (int i = tid; i < 769*ROWS; i += 256){ (&yyT[0][0])[i] = 0.f; (&wwT[0][0])[i] = 0.f; }
    for (int i = tid; i < 36*ROWS*20; i += 256) (&crb[0][0][0])[i] = 0.f;
    if (tid < 2*ROWS*20){ (&mid[0][0][0])[tid] = 0.f; (&xpv[0][0][0])[tid] = 0.f; }
    if (tid < ROWS*20) (&tmv[0][0])[tid] = 0.f;
    if (tid < 12*ROWS){ int r = tid/12, k = tid%12; pr[r][k] = (k < 9) ? feat[(b0+r)*12 + 3 + k] : 0.f; }
    if (tid < ROWS){
        float s0 = feat[(b0+tid)*12 + 0], s1 = feat[(b0+tid)*12 + 1];
        #pragma unroll
        for (int j = 0; j < 8; ++j) zi[tid][j] = s0*XtoZ[j*2 + 0] + s1*XtoZ[j*2 + 1];
        zi[tid][8] = feat[(b0+tid)*12 + 2];
    }
    __syncthreads();

    for (int it = 0; it < NITERS; ++it){
        // -------- phase A: rhs = sigma*x - q + w@A (packed CSC, float4 row loads) --------
        for (int c = tid; c < 502; c += 256){
            float r0 = SIGMA*buf[c][0], r1 = SIGMA*buf[c][1];
            int t14 = c/14, s14 = c - t14*14;
            if (c < 490 && s14 == 9){ int pi = t14 >> 2; r0 -= pr[0][pi]; r1 -= pr[1][pi]; }
            const float4* pp = (const float4*)(ws + OFF_CSCP + c*32);
            #pragma unroll
            for (int s = 0; s < 8; ++s){
                float4 p4 = pp[s];
                int ra = __float_as_int(p4.y), rb = __float_as_int(p4.w);
                r0 += p4.x*wwT[ra][0]; r1 += p4.x*wwT[ra][1];
                r0 += p4.z*wwT[rb][0]; r1 += p4.z*wwT[rb][1];
            }
            buf[c][0] = r0; buf[c][1] = r1;
        }
        __syncthreads();
        // -------- twisted block-tridiag solve (wave 0, 64 lanes) --------
        if (tid < 64){
            const int li  = tid & 15;
            const int lr  = (tid >> 4) & 1;
            const int dir = tid >> 5;
            {
                int ti = dir ? 35 : 0;
                crb[ti][lr][li] = (li < 14) ? buf[14*ti + li][lr] : 0.f;
            }
            const float* EB = dir ? (ws + OFF_HP) : (ws + OFF_GP);
            float4 g0, g1, g2, g3;
            { int t0 = dir ? 34 : 1; LD4X4(EB + t0*256 + li*16, g0, g1, g2, g3) }
            for (int k = 0; k < 17; ++k){
                bool act  = dir ? true : (k <= 15);
                int t     = dir ? (34 - k) : (k + 1);
                int tp    = dir ? (t + 1) : (t - 1);
                bool nact = dir ? ((k+1) <= 16) : ((k+1) <= 15);
                int tn    = nact ? (dir ? (34 - (k+1)) : (k + 2)) : t;
                float4 n0, n1, n2, n3;
                LD4X4(EB + tn*256 + li*16, n0, n1, n2, n3)
                float4 c0, c1, c2, c3;
                LD4X4(&crb[tp][lr][0], c0, c1, c2, c3)
                float b = (act && li < 14) ? buf[14*t + li][lr] : 0.f;
                float a0 = 0.f, a1 = 0.f;
                DOT16(a0, a1, g0, g1, g2, g3, c0, c1, c2, c3)
                float nc = b - a0 - a1;
                if (act) crb[t][lr][li] = nc;
                g0 = n0; g1 = n1; g2 = n2; g3 = n3;
            }
            // meet: x_m = W (b_m - G_m c_{m-1} - H_m d_{m+1})
            {
                const float* mr = (dir ? (ws + OFF_HP) : (ws + OFF_GP)) + MEET*256 + li*16;
                float4 m0, m1, m2, m3;  LD4X4(mr, m0, m1, m2, m3)
                int tc = dir ? (MEET + 1) : (MEET - 1);
                float4 c0, c1, c2, c3;  LD4X4(&crb[tc][lr][0], c0, c1, c2, c3)
                float p0 = 0.f, p1 = 0.f;
                DOT16(p0, p1, m0, m1, m2, m3, c0, c1, c2, c3)
                mid[dir][lr][li] = p0 + p1;
                float bm = (li < 14) ? buf[14*MEET + li][lr] : 0.f;
                float tv = bm - mid[0][lr][li] - mid[1][lr][li];
                if (!dir) tmv[lr][li] = tv;
                float4 w0, w1, w2, w3;  LD4X4(ws + OFF_WP + li*16, w0, w1, w2, w3)
                float4 t0, t1, t2, t3;  LD4X4(&tmv[lr][0], t0, t1, t2, t3)
                float a0 = 0.f, a1 = 0.f;
                DOT16(a0, a1, w0, w1, w2, w3, t0, t1, t2, t3)
                float xm = a0 + a1;
                xpv[dir][lr][li] = xm;
                if (!dir && li < 14) buf[14*MEET + li][lr] = xm;
            }
            // back-sub outward
            const float* SB = dir ? (ws + OFF_SVTP) : (ws + OFF_SVP);
            const float* KB = dir ? (ws + OFF_KP)   : (ws + OFF_GTP);
            for (int k = 0; k < 18; ++k){
                bool act = dir ? true : (k <= 16);
                int t   = dir ? (MEET + 1 + k) : (MEET - 1 - k);
                int tc  = act ? t : 0;
                int tk  = dir ? tc : (tc + 1);
                float4 s0, s1, s2, s3;  LD4X4(SB + tc*256 + li*16, s0, s1, s2, s3)
                float4 k0, k1, k2, k3;  LD4X4(KB + tk*256 + li*16, k0, k1, k2, k3)
                float4 c0, c1, c2, c3;  LD4X4(&crb[tc][lr][0], c0, c1, c2, c3)
                float4 x0, x1, x2, x3;  LD4X4(&xpv[dir][lr][0], x0, x1, x2, x3)
                float a0 = 0.f, a1 = 0.f, d0 = 0.f, d1 = 0.f;
                DOT16(a0, a1, s0, s1, s2, s3, c0, c1, c2, c3)
                DOT16(d0, d1, k0, k1, k2, k3, x0, x1, x2, x3)
                float x = (a0 + a1) - (d0 + d1);
                if (act){
                    xpv[dir][lr][li] = x;
                    if (li < 14) buf[14*t + li][lr] = x;
                }
            }
        }
        __syncthreads();
        // -------- phase B: Ax (packed CSR), clip, y/w update --------
        for (int rr = tid; rr < 769; rr += 256){
            float rho = rho_of(rr);
            float rinv = 1.f/rho;
            float ax0 = 0.f, ax1 = 0.f;
            const float4* pp = (const float4*)(ws + OFF_CSRP + rr*24);
            #pragma unroll
            for (int s = 0; s < 6; ++s){
                float4 p4 = pp[s];
                int ca = __float_as_int(p4.y), cb = __float_as_int(p4.w);
                ax0 += p4.x*buf[ca][0]; ax1 += p4.x*buf[ca][1];
                ax0 += p4.z*buf[cb][0]; ax1 += p4.z*buf[cb][1];
            }
            float lb = 0.f, ub = 0.f;
            if (rr >= 9){ lb = l0s[rr]; ub = u0s[rr]; }
            float yv0 = yyT[rr][0], yv1 = yyT[rr][1];
            float li0, ui0, li1, ui1;
            if (rr < 9){ li0 = ui0 = zi[0][rr]; li1 = ui1 = zi[1][rr]; }
            else { li0 = li1 = lb; ui0 = ui1 = ub; }
            float v0 = ax0 + yv0*rinv;
            float v1 = ax1 + yv1*rinv;
            float z0 = fminf(fmaxf(v0, li0), ui0);
            float z1 = fminf(fmaxf(v1, li1), ui1);
            float yn0 = yv0 + rho*(ax0 - z0);
            float yn1 = yv1 + rho*(ax1 - z1);
            yyT[rr][0] = yn0; yyT[rr][1] = yn1;
            wwT[rr][0] = rho*z0 - yn0; wwT[rr][1] = rho*z1 - yn1;
        }
        __syncthreads();
    }
    if (tid < ROWS*2){ int r = tid >> 1, k = tid & 1; out[(b0 + r)*2 + k] = buf[8 + k][r]; }
}

// ---------------- K8: critic MLP ----------------
__global__ __launch_bounds__(64) void k_critic(const float* __restrict__ feat,
    const float* __restrict__ Ws,  const float* __restrict__ bs_,
    const float* __restrict__ Wst, const float* __restrict__ bst,
    const float* __restrict__ Wipr,const float* __restrict__ bipr,
    const float* __restrict__ Wp,  const float* __restrict__ bp,
    const float* __restrict__ Ws1, const float* __restrict__ bs1,
    const float* __restrict__ Wst1,const float* __restrict__ bst1,
    const float* __restrict__ Wipr1,const float* __restrict__ bipr1,
    const float* __restrict__ Wp1, const float* __restrict__ bp1,
    const float* __restrict__ Wf1, const float* __restrict__ bf1,
    const float* __restrict__ Wf2, const float* __restrict__ bf2,
    float* __restrict__ out){
    __shared__ float hL[64][65];
    __shared__ float h2L[64][65];
    int tid = threadIdx.x;
    int b = blockIdx.x*64 + tid;
    const float* f = feat + b*12;
    float st0 = f[0], st1 = f[1], sg = f[2];
    float p[9];
    #pragma unroll
    for (int j = 0; j < 9; ++j) p[j] = f[3 + j];
    float pmx = p[0], pmn = p[0];
    #pragma unroll
    for (int j = 1; j < 9; ++j){ pmx = fmaxf(pmx, p[j]); pmn = fminf(pmn, p[j]); }
    float t1[24], t2[8];
    #pragma unroll
    for (int o = 0; o < 24; ++o) t1[o] = fmaxf(0.f, st0*Ws[o*2] + st1*Ws[o*2 + 1] + bs_[o]);
    #pragma unroll
    for (int o = 0; o < 24; ++o){ float a = bs1[o];
        #pragma unroll
        for (int j = 0; j < 24; ++j) a += t1[j]*Ws1[o*24 + j];
        hL[tid][o] = fmaxf(0.f, a); }
    #pragma unroll
    for (int o = 0; o < 8; ++o) t2[o] = fmaxf(0.f, sg*Wst[o] + bst[o]);
    #pragma unroll
    for (int o = 0; o < 8; ++o){ float a = bst1[o];
        #pragma unroll
        for (int j = 0; j < 8; ++j) a += t2[j]*Wst1[o*8 + j];
        hL[tid][24 + o] = fmaxf(0.f, a); }
    float i1 = pmx - pmn;
    #pragma unroll
    for (int o = 0; o < 8; ++o) t2[o] = fmaxf(0.f, p[0]*Wipr[o*2] + i1*Wipr[o*2 + 1] + bipr[o]);
    #pragma unroll
    for (int o = 0; o < 8; ++o){ float a = bipr1[o];
        #pragma unroll
        for (int j = 0; j < 8; ++j) a += t2[j]*Wipr1[o*8 + j];
        hL[tid][32 + o] = fmaxf(0.f, a); }
    #pragma unroll
    for (int o = 0; o < 24; ++o){ float a = bp[o];
        #pragma unroll
        for (int j = 0; j < 9; ++j) a += p[j]*Wp[o*9 + j];
        t1[o] = fmaxf(0.f, a); }
    #pragma unroll
    for (int o = 0; o < 24; ++o){ float a = bp1[o];
        #pragma unroll
        for (int j = 0; j < 24; ++j) a += t1[j]*Wp1[o*24 + j];
        hL[tid][40 + o] = fmaxf(0.f, a); }
    for (int o = 0; o < 64; ++o){ float a = bf1[o];
        for (int j = 0; j < 64; ++j) a += hL[tid][j]*Wf1[o*64 + j];
        h2L[tid][o] = fmaxf(0.f, a); }
    for (int o = 0; o < 64; ++o){ float a = bf2[o];
        for (int j = 0; j < 64; ++j) a += h2L[tid][j]*Wf2[o*64 + j];
        out[2048 + b*64 + o] = fmaxf(0.f, a); }
}

extern "C" void kernel_launch(void* const* d_in, const int* in_sizes, int n_in,
                              void* d_out, int out_size, void* d_ws, size_t ws_size,
                              hipStream_t stream){
    (void)in_sizes; (void)n_in; (void)out_size; (void)ws_size;
    const float* feat  = (const float*)d_in[0];
    const float* Xlb_p = (const float*)d_in[1];
    const float* Xub_p = (const float*)d_in[2];
    const float* slb_p = (const float*)d_in[3];
    const float* sub_p = (const float*)d_in[4];
    const float* tgt_p = (const float*)d_in[5];
    const float* Az    = (const float*)d_in[6];
    const float* Au    = (const float*)d_in[7];
    const float* ZtoX  = (const float*)d_in[8];
    const float* XtoZ  = (const float*)d_in[9];
    float* ws  = (float*)d_ws;
    float* out = (float*)d_out;

    hipLaunchKernelGGL(k_build_A,     dim3(1),    dim3(256), 0, stream, Az, Au, ZtoX, ws);
    hipLaunchKernelGGL(k_sparse,      dim3(5),    dim3(256), 0, stream, ws);
    hipLaunchKernelGGL(k_build_M,     dim3(1004), dim3(256), 0, stream, ws);
    hipLaunchKernelGGL(k_factor_both, dim3(2),    dim3(256), 0, stream, ws);
    hipLaunchKernelGGL(k_meet,        dim3(1),    dim3(256), 0, stream, ws);
    hipLaunchKernelGGL(k_finish,      dim3(105),  dim3(256), 0, stream, Xlb_p, Xub_p, slb_p, sub_p, tgt_p, ws);
    hipLaunchKernelGGL(k_admm,        dim3(512),  dim3(256), 0, stream, feat, XtoZ, ws, out);
    hipLaunchKernelGGL(k_critic,      dim3(16),   dim3(64),  0, stream, feat,
        (const float*)d_in[10], (const float*)d_in[11], (const float*)d_in[12], (const float*)d_in[13],
        (const float*)d_in[14], (const float*)d_in[15], (const float*)d_in[16], (const float*)d_in[17],
        (const float*)d_in[18], (const float*)d_in[19], (const float*)d_in[20], (const float*)d_in[21],
        (const float*)d_in[22], (const float*)d_in[23], (const float*)d_in[24], (const float*)d_in[25],
        (const float*)d_in[26], (const float*)d_in[27], (const float*)d_in[28], (const float*)d_in[29],
        out);
}